// Round 2
// baseline (156.640 us; speedup 1.0000x reference)
//
#include <hip/hip_runtime.h>
#include <math.h>

// Problem constants (fixed by the reference)
#define LN 512
#define RN 4096
#define EN 32
#define FN 64

// Tile config: block = 16x16 threads, pair tile = 64 (l) x 128 (r),
// thread sub-tile = 4 (l) x 8 (r). grid.z splits the 32 rbf steps in halves.
#define BL 64
#define BR 128
#define EH 16
#define LDS_STRIDE 68  // 64 + 4 floats pad: keeps float4 alignment, breaks bank conflicts

// exp(-16*t^2) = exp2(-16*log2(e)*t^2)
#define NEG16_LOG2E 23.083120654223415f
#define MU_STEP (8.0f / 31.0f)

__global__ __launch_bounds__(256) void ff_main(
    const float* __restrict__ lig_feat,   // [L][E][F]
    const float* __restrict__ rec_feat,   // [R][E][F]
    const float* __restrict__ lig_coord,  // [L][3]
    const float* __restrict__ rec_coord,  // [R][3]
    float* __restrict__ partial)          // [gridDim.z*gridDim.y*gridDim.x]
{
    __shared__ float ligs[BL][LDS_STRIDE];
    __shared__ float recs[BR][LDS_STRIDE];

    const int tx = threadIdx.x;           // 0..15
    const int ty = threadIdx.y;           // 0..15
    const int tid = ty * 16 + tx;
    const int r0 = blockIdx.x * BR;
    const int l0 = blockIdx.y * BL;
    const int e0 = blockIdx.z * EH;

    // ---- pairwise distances for this thread's 4x8 sub-tile ----
    float d[4][8];
    {
        float lcx[4], lcy[4], lcz[4];
        #pragma unroll
        for (int i = 0; i < 4; ++i) {
            const int l = l0 + ty + 16 * i;
            lcx[i] = lig_coord[l * 3 + 0];
            lcy[i] = lig_coord[l * 3 + 1];
            lcz[i] = lig_coord[l * 3 + 2];
        }
        #pragma unroll
        for (int j = 0; j < 8; ++j) {
            const int r = r0 + tx + 16 * j;
            const float rx = rec_coord[r * 3 + 0];
            const float ry = rec_coord[r * 3 + 1];
            const float rz = rec_coord[r * 3 + 2];
            #pragma unroll
            for (int i = 0; i < 4; ++i) {
                const float dx = lcx[i] - rx;
                const float dy = lcy[i] - ry;
                const float dz = lcz[i] - rz;
                d[i][j] = sqrtf(fmaf(dx, dx, fmaf(dy, dy, dz * dz)));
            }
        }
    }

    float usum = 0.0f;

    for (int ee = 0; ee < EH; ++ee) {
        const int e = e0 + ee;

        __syncthreads();  // protect LDS from previous iteration's readers

        // ---- stage lig tile: 64 rows x 64 f = 1024 float4, 4 per thread ----
        #pragma unroll
        for (int c = 0; c < 4; ++c) {
            const int idx = c * 256 + tid;
            const int row = idx >> 4;       // 0..63
            const int f4  = idx & 15;       // 0..15
            const float4 v = *(const float4*)&lig_feat[((size_t)(l0 + row) * EN + e) * FN + f4 * 4];
            *(float4*)&ligs[row][f4 * 4] = v;
        }
        // ---- stage rec tile: 128 rows x 64 f = 2048 float4, 8 per thread ----
        #pragma unroll
        for (int c = 0; c < 8; ++c) {
            const int idx = c * 256 + tid;
            const int row = idx >> 4;       // 0..127
            const int f4  = idx & 15;
            const float4 v = *(const float4*)&rec_feat[((size_t)(r0 + row) * EN + e) * FN + f4 * 4];
            *(float4*)&recs[row][f4 * 4] = v;
        }
        __syncthreads();

        // ---- accumulate dot over f for this e ----
        float acc[4][8];
        #pragma unroll
        for (int i = 0; i < 4; ++i)
            #pragma unroll
            for (int j = 0; j < 8; ++j) acc[i][j] = 0.0f;

        #pragma unroll 4
        for (int f4 = 0; f4 < 16; ++f4) {
            float4 a[4], b[8];
            #pragma unroll
            for (int i = 0; i < 4; ++i) a[i] = *(const float4*)&ligs[ty + 16 * i][f4 * 4];
            #pragma unroll
            for (int j = 0; j < 8; ++j) b[j] = *(const float4*)&recs[tx + 16 * j][f4 * 4];
            #pragma unroll
            for (int i = 0; i < 4; ++i) {
                #pragma unroll
                for (int j = 0; j < 8; ++j) {
                    acc[i][j] = fmaf(a[i].x, b[j].x, acc[i][j]);
                    acc[i][j] = fmaf(a[i].y, b[j].y, acc[i][j]);
                    acc[i][j] = fmaf(a[i].z, b[j].z, acc[i][j]);
                    acc[i][j] = fmaf(a[i].w, b[j].w, acc[i][j]);
                }
            }
        }

        // ---- fold rbf weight into running sum ----
        const float mu = (float)e * MU_STEP;
        #pragma unroll
        for (int i = 0; i < 4; ++i) {
            #pragma unroll
            for (int j = 0; j < 8; ++j) {
                const float t = d[i][j] - mu;
                usum = fmaf(acc[i][j], exp2f(-NEG16_LOG2E * t * t), usum);
            }
        }
    }

    // ---- block reduction (reuse ligs as scratch) ----
    __syncthreads();
    float* red = &ligs[0][0];
    red[tid] = usum;
    __syncthreads();
    #pragma unroll
    for (int st = 128; st > 0; st >>= 1) {
        if (tid < st) red[tid] += red[tid + st];
        __syncthreads();
    }
    if (tid == 0) {
        const int bidx = (blockIdx.z * gridDim.y + blockIdx.y) * gridDim.x + blockIdx.x;
        partial[bidx] = red[0];
    }
}

__global__ __launch_bounds__(256) void ff_reduce(
    const float* __restrict__ partial, float* __restrict__ out, int n)
{
    __shared__ float s[256];
    float v = 0.0f;
    for (int i = threadIdx.x; i < n; i += 256) v += partial[i];
    s[threadIdx.x] = v;
    __syncthreads();
    #pragma unroll
    for (int st = 128; st > 0; st >>= 1) {
        if (threadIdx.x < st) s[threadIdx.x] += s[threadIdx.x + st];
        __syncthreads();
    }
    if (threadIdx.x == 0) out[0] = s[0] * 0.01f;
}

extern "C" void kernel_launch(void* const* d_in, const int* in_sizes, int n_in,
                              void* d_out, int out_size, void* d_ws, size_t ws_size,
                              hipStream_t stream)
{
    const float* lig_feat  = (const float*)d_in[0];
    const float* rec_feat  = (const float*)d_in[1];
    const float* lig_coord = (const float*)d_in[2];
    const float* rec_coord = (const float*)d_in[3];
    float* out = (float*)d_out;
    float* partial = (float*)d_ws;

    const dim3 grid(RN / BR, LN / BL, EN / EH);  // (32, 8, 2) = 512 blocks
    const dim3 block(16, 16);
    ff_main<<<grid, block, 0, stream>>>(lig_feat, rec_feat, lig_coord, rec_coord, partial);

    const int nPartial = (RN / BR) * (LN / BL) * (EN / EH);  // 512
    ff_reduce<<<1, 256, 0, stream>>>(partial, out, nPartial);
}

// Round 3
// 62.551 us; speedup vs baseline: 2.5042x; 2.5042x over previous
//
#include <hip/hip_runtime.h>
#include <math.h>

// Problem constants
#define LN 512
#define RN 4096
#define EN 32
#define FN 64

// Tiling: 128(l) x 128(r) pair tile per block, 4 waves, each wave owns a
// 4x4 grid of 16x16 MFMA tiles (64x64 quadrant). EH rbf steps per block.
#define BLT 128
#define BRT 128
#define EH  8

#define K16LOG2E 23.083120654223415f   // 16*log2(e):  exp(-16 t^2) = exp2(-K*t^2)
#define MU_STEP (8.0f / 31.0f)

typedef __attribute__((ext_vector_type(8))) short short8;   // 8 bf16 = 4 VGPR (MFMA A/B frag)
typedef __attribute__((ext_vector_type(4))) float f32x4;    // MFMA C/D frag

// LDS: 4 planes of 128 rows x 64 bf16 (128B rows, no pad — XOR swizzle instead)
#define PLANE (128 * 128)
#define AHI 0
#define ALO PLANE
#define BHI (2 * PLANE)
#define BLO (3 * PLANE)
#define LDS_BYTES (4 * PLANE)   // 65536

// fp32 -> bf16 round-to-nearest-even (inputs are finite normals; no NaN path)
__device__ __forceinline__ unsigned short f2bf(float x) {
    unsigned u = __builtin_bit_cast(unsigned, x);
    u += 0x7FFFu + ((u >> 16) & 1u);
    return (unsigned short)(u >> 16);
}
__device__ __forceinline__ float bf2f(unsigned short h) {
    unsigned u = ((unsigned)h) << 16;
    return __builtin_bit_cast(float, u);
}

__global__ __launch_bounds__(256, 2) void ff_mfma(
    const float* __restrict__ lig_feat,   // [L][E][F]
    const float* __restrict__ rec_feat,   // [R][E][F]
    const float* __restrict__ lig_coord,  // [L][3]
    const float* __restrict__ rec_coord,  // [R][3]
    float* __restrict__ partial)
{
    extern __shared__ char lds[];

    const int tid  = threadIdx.x;
    const int lane = tid & 63;
    const int w    = tid >> 6;
    const int wl   = (w >> 1) * 4;     // wave's base tile-row (of 8)
    const int wr   = (w & 1) * 4;      // wave's base tile-col (of 8)
    const int lrow = lane & 15;        // A-row / B-col within 16x16 tile
    const int lk   = lane >> 4;        // k-group 0..3

    const int l0 = blockIdx.y * BLT;
    const int r0 = blockIdx.x * BRT;
    const int e0 = blockIdx.z * EH;

    // ---- distances, computed once, reused for all EH steps ----
    // C/D layout (m89-verified): col = lane&15 (-> r), row = (lane>>4)*4 + reg (-> l)
    float rcx[4], rcy[4], rcz[4];
    #pragma unroll
    for (int tj = 0; tj < 4; ++tj) {
        const int r = r0 + (wr + tj) * 16 + lrow;
        rcx[tj] = rec_coord[r * 3 + 0];
        rcy[tj] = rec_coord[r * 3 + 1];
        rcz[tj] = rec_coord[r * 3 + 2];
    }
    float d[4][4][4];   // [ti][tj][reg]
    #pragma unroll
    for (int ti = 0; ti < 4; ++ti) {
        #pragma unroll
        for (int i = 0; i < 4; ++i) {
            const int l = l0 + (wl + ti) * 16 + lk * 4 + i;
            const float lx = lig_coord[l * 3 + 0];
            const float ly = lig_coord[l * 3 + 1];
            const float lz = lig_coord[l * 3 + 2];
            #pragma unroll
            for (int tj = 0; tj < 4; ++tj) {
                const float dx = lx - rcx[tj];
                const float dy = ly - rcy[tj];
                const float dz = lz - rcz[tj];
                d[ti][tj][i] = sqrtf(fmaf(dx, dx, fmaf(dy, dy, dz * dz)));
            }
        }
    }

    float usum = 0.0f;

    for (int ee = 0; ee < EH; ++ee) {
        const int e = e0 + ee;

        __syncthreads();   // previous iteration's readers done

        // ---- stage: fp32 -> (hi,lo) bf16 planes, XOR-swizzled rows ----
        // 4096 float4 per (block,e): 16 per thread. k<8 -> lig, k>=8 -> rec.
        #pragma unroll
        for (int k = 0; k < 16; ++k) {
            const int idx = k * 256 + tid;
            const int row = (idx >> 4) & 127;
            const int c   = idx & 15;
            const float4 v = (k < 8)
                ? *(const float4*)&lig_feat[((l0 + row) * EN + e) * FN + c * 4]
                : *(const float4*)&rec_feat[((r0 + row) * EN + e) * FN + c * 4];

            const unsigned short h0 = f2bf(v.x), h1 = f2bf(v.y),
                                 h2 = f2bf(v.z), h3 = f2bf(v.w);
            const unsigned short q0 = f2bf(v.x - bf2f(h0)), q1 = f2bf(v.y - bf2f(h1)),
                                 q2 = f2bf(v.z - bf2f(h2)), q3 = f2bf(v.w - bf2f(h3));
            uint2 hw, lw;
            hw.x = (unsigned)h0 | ((unsigned)h1 << 16);
            hw.y = (unsigned)h2 | ((unsigned)h3 << 16);
            lw.x = (unsigned)q0 | ((unsigned)q1 << 16);
            lw.y = (unsigned)q2 | ((unsigned)q3 << 16);

            const int off = row * 128 + ((c * 8) ^ ((row & 7) << 4));
            *(uint2*)(lds + ((k < 8) ? AHI : BHI) + off) = hw;
            *(uint2*)(lds + ((k < 8) ? ALO : BLO) + off) = lw;
        }
        __syncthreads();

        // ---- 3-product split-bf16 MFMA over f=64 (2 k-chunks of 32) ----
        f32x4 acc[4][4];
        #pragma unroll
        for (int ti = 0; ti < 4; ++ti)
            #pragma unroll
            for (int tj = 0; tj < 4; ++tj)
                acc[ti][tj] = (f32x4){0.f, 0.f, 0.f, 0.f};

        #pragma unroll
        for (int kc = 0; kc < 2; ++kc) {
            const int inrow = (kc * 64 + lk * 16) ^ ((lrow & 7) << 4);
            short8 ahf[4], alf[4], bhf[4], blf[4];
            #pragma unroll
            for (int t = 0; t < 4; ++t) {
                const int arow = (wl + t) * 16 + lrow;
                const int brow = (wr + t) * 16 + lrow;
                ahf[t] = *(const short8*)(lds + AHI + arow * 128 + inrow);
                alf[t] = *(const short8*)(lds + ALO + arow * 128 + inrow);
                bhf[t] = *(const short8*)(lds + BHI + brow * 128 + inrow);
                blf[t] = *(const short8*)(lds + BLO + brow * 128 + inrow);
            }
            #pragma unroll
            for (int ti = 0; ti < 4; ++ti) {
                #pragma unroll
                for (int tj = 0; tj < 4; ++tj) {
                    acc[ti][tj] = __builtin_amdgcn_mfma_f32_16x16x32_bf16(
                        ahf[ti], bhf[tj], acc[ti][tj], 0, 0, 0);
                    acc[ti][tj] = __builtin_amdgcn_mfma_f32_16x16x32_bf16(
                        alf[ti], bhf[tj], acc[ti][tj], 0, 0, 0);
                    acc[ti][tj] = __builtin_amdgcn_mfma_f32_16x16x32_bf16(
                        ahf[ti], blf[tj], acc[ti][tj], 0, 0, 0);
                }
            }
        }

        // ---- rbf weight + accumulate ----
        const float mu = (float)e * MU_STEP;
        #pragma unroll
        for (int ti = 0; ti < 4; ++ti) {
            #pragma unroll
            for (int tj = 0; tj < 4; ++tj) {
                #pragma unroll
                for (int i = 0; i < 4; ++i) {
                    const float t = d[ti][tj][i] - mu;
                    const float wgt = __builtin_amdgcn_exp2f(-K16LOG2E * t * t);
                    usum = fmaf(acc[ti][tj][i], wgt, usum);
                }
            }
        }
    }

    // ---- block reduction (reuse LDS) ----
    __syncthreads();
    float* red = (float*)lds;
    red[tid] = usum;
    __syncthreads();
    #pragma unroll
    for (int st = 128; st > 0; st >>= 1) {
        if (tid < st) red[tid] += red[tid + st];
        __syncthreads();
    }
    if (tid == 0) {
        const int bidx = (blockIdx.z * gridDim.y + blockIdx.y) * gridDim.x + blockIdx.x;
        partial[bidx] = red[0];
    }
}

__global__ __launch_bounds__(256) void ff_reduce(
    const float* __restrict__ partial, float* __restrict__ out, int n)
{
    __shared__ float s[256];
    float v = 0.0f;
    for (int i = threadIdx.x; i < n; i += 256) v += partial[i];
    s[threadIdx.x] = v;
    __syncthreads();
    #pragma unroll
    for (int st = 128; st > 0; st >>= 1) {
        if (threadIdx.x < st) s[threadIdx.x] += s[threadIdx.x + st];
        __syncthreads();
    }
    if (threadIdx.x == 0) out[0] = s[0] * 0.01f;
}

extern "C" void kernel_launch(void* const* d_in, const int* in_sizes, int n_in,
                              void* d_out, int out_size, void* d_ws, size_t ws_size,
                              hipStream_t stream)
{
    const float* lig_feat  = (const float*)d_in[0];
    const float* rec_feat  = (const float*)d_in[1];
    const float* lig_coord = (const float*)d_in[2];
    const float* rec_coord = (const float*)d_in[3];
    float* out = (float*)d_out;
    float* partial = (float*)d_ws;

    const dim3 grid(RN / BRT, LN / BLT, EN / EH);   // (32, 4, 4) = 512 blocks
    ff_mfma<<<grid, dim3(256), LDS_BYTES, stream>>>(
        lig_feat, rec_feat, lig_coord, rec_coord, partial);

    const int nPartial = (RN / BRT) * (LN / BLT) * (EN / EH);   // 512
    ff_reduce<<<1, 256, 0, stream>>>(partial, out, nPartial);
}

// Round 4
// 39.979 us; speedup vs baseline: 3.9181x; 1.5646x over previous
//
#include <hip/hip_runtime.h>
#include <math.h>

// Problem constants
#define LN 512
#define RN 4096
#define EN 32
#define FN 64

// Tiling: 128(l) x 128(r) pair tile per block, 4 waves, each wave owns a
// 4x4 grid of 16x16 MFMA tiles (64x64 quadrant). EH rbf steps per block.
#define BLT 128
#define BRT 128
#define EH  8

#define K16LOG2E 23.083120654223415f   // 16*log2(e):  exp(-16 t^2) = exp2(-K*t^2)
#define MU_STEP (8.0f / 31.0f)

typedef _Float16 half8 __attribute__((ext_vector_type(8)));  // MFMA A/B frag (4 VGPR)
typedef __attribute__((ext_vector_type(4))) float f32x4;     // MFMA C/D frag

// LDS: 2 planes of 128 rows x 64 f16 (128B rows, XOR-swizzled)
#define APLANE 0
#define BPLANE (128 * 128)
#define LDS_BYTES (2 * 128 * 128)   // 32768

__global__ __launch_bounds__(256, 2) void ff_mfma(
    const float* __restrict__ lig_feat,   // [L][E][F]
    const float* __restrict__ rec_feat,   // [R][E][F]
    const float* __restrict__ lig_coord,  // [L][3]
    const float* __restrict__ rec_coord,  // [R][3]
    float* __restrict__ partial)
{
    extern __shared__ char lds[];

    const int tid  = threadIdx.x;
    const int lane = tid & 63;
    const int w    = tid >> 6;
    const int wl   = (w >> 1) * 4;     // wave's base tile-row (of 8)
    const int wr   = (w & 1) * 4;      // wave's base tile-col (of 8)
    const int lrow = lane & 15;        // A-row / B-col within 16x16 tile
    const int lk   = lane >> 4;        // k-group 0..3

    const int l0 = blockIdx.y * BLT;
    const int r0 = blockIdx.x * BRT;
    const int e0 = blockIdx.z * EH;

    // ---- distances, computed once, reused for all EH steps ----
    // C/D layout (m89-verified): col = lane&15 (-> r), row = (lane>>4)*4 + reg (-> l)
    float rcx[4], rcy[4], rcz[4];
    #pragma unroll
    for (int tj = 0; tj < 4; ++tj) {
        const int r = r0 + (wr + tj) * 16 + lrow;
        rcx[tj] = rec_coord[r * 3 + 0];
        rcy[tj] = rec_coord[r * 3 + 1];
        rcz[tj] = rec_coord[r * 3 + 2];
    }
    float d[4][4][4];   // [ti][tj][reg]
    #pragma unroll
    for (int ti = 0; ti < 4; ++ti) {
        #pragma unroll
        for (int i = 0; i < 4; ++i) {
            const int l = l0 + (wl + ti) * 16 + lk * 4 + i;
            const float lx = lig_coord[l * 3 + 0];
            const float ly = lig_coord[l * 3 + 1];
            const float lz = lig_coord[l * 3 + 2];
            #pragma unroll
            for (int tj = 0; tj < 4; ++tj) {
                const float dx = lx - rcx[tj];
                const float dy = ly - rcy[tj];
                const float dz = lz - rcz[tj];
                d[ti][tj][i] = sqrtf(fmaf(dx, dx, fmaf(dy, dy, dz * dz)));
            }
        }
    }

    float usum = 0.0f;

    for (int ee = 0; ee < EH; ++ee) {
        const int e = e0 + ee;

        __syncthreads();   // previous iteration's readers done

        // ---- stage: fp32 -> f16 planes (RTE), XOR-swizzled rows ----
        // 4096 float4 per (block,e): 16 per thread. k<8 -> lig, k>=8 -> rec.
        #pragma unroll
        for (int k = 0; k < 16; ++k) {
            const int idx = k * 256 + tid;
            const int row = (idx >> 4) & 127;
            const int c   = idx & 15;
            const float4 v = (k < 8)
                ? *(const float4*)&lig_feat[((l0 + row) * EN + e) * FN + c * 4]
                : *(const float4*)&rec_feat[((r0 + row) * EN + e) * FN + c * 4];

            const unsigned short h0 = __builtin_bit_cast(unsigned short, (_Float16)v.x);
            const unsigned short h1 = __builtin_bit_cast(unsigned short, (_Float16)v.y);
            const unsigned short h2 = __builtin_bit_cast(unsigned short, (_Float16)v.z);
            const unsigned short h3 = __builtin_bit_cast(unsigned short, (_Float16)v.w);
            uint2 hw;
            hw.x = (unsigned)h0 | ((unsigned)h1 << 16);
            hw.y = (unsigned)h2 | ((unsigned)h3 << 16);

            const int off = row * 128 + ((c * 8) ^ ((row & 7) << 4));
            *(uint2*)(lds + ((k < 8) ? APLANE : BPLANE) + off) = hw;
        }
        __syncthreads();

        // ---- single-product f16 MFMA over f=64 (2 k-chunks of 32) ----
        f32x4 acc[4][4];
        #pragma unroll
        for (int ti = 0; ti < 4; ++ti)
            #pragma unroll
            for (int tj = 0; tj < 4; ++tj)
                acc[ti][tj] = (f32x4){0.f, 0.f, 0.f, 0.f};

        #pragma unroll
        for (int kc = 0; kc < 2; ++kc) {
            const int inrow = (kc * 64 + lk * 16) ^ ((lrow & 7) << 4);
            half8 af[4], bf_[4];
            #pragma unroll
            for (int t = 0; t < 4; ++t) {
                const int arow = (wl + t) * 16 + lrow;
                const int brow = (wr + t) * 16 + lrow;
                af[t]  = *(const half8*)(lds + APLANE + arow * 128 + inrow);
                bf_[t] = *(const half8*)(lds + BPLANE + brow * 128 + inrow);
            }
            #pragma unroll
            for (int ti = 0; ti < 4; ++ti) {
                #pragma unroll
                for (int tj = 0; tj < 4; ++tj) {
                    acc[ti][tj] = __builtin_amdgcn_mfma_f32_16x16x32_f16(
                        af[ti], bf_[tj], acc[ti][tj], 0, 0, 0);
                }
            }
        }

        // ---- rbf weight + accumulate ----
        const float mu = (float)e * MU_STEP;
        #pragma unroll
        for (int ti = 0; ti < 4; ++ti) {
            #pragma unroll
            for (int tj = 0; tj < 4; ++tj) {
                #pragma unroll
                for (int i = 0; i < 4; ++i) {
                    const float t = d[ti][tj][i] - mu;
                    const float wgt = __builtin_amdgcn_exp2f(-K16LOG2E * t * t);
                    usum = fmaf(acc[ti][tj][i], wgt, usum);
                }
            }
        }
    }

    // ---- block reduction (reuse LDS) ----
    __syncthreads();
    float* red = (float*)lds;
    red[tid] = usum;
    __syncthreads();
    #pragma unroll
    for (int st = 128; st > 0; st >>= 1) {
        if (tid < st) red[tid] += red[tid + st];
        __syncthreads();
    }
    if (tid == 0) {
        const int bidx = (blockIdx.z * gridDim.y + blockIdx.y) * gridDim.x + blockIdx.x;
        partial[bidx] = red[0];
    }
}

__global__ __launch_bounds__(256) void ff_reduce(
    const float* __restrict__ partial, float* __restrict__ out, int n)
{
    __shared__ float s[256];
    float v = 0.0f;
    for (int i = threadIdx.x; i < n; i += 256) v += partial[i];
    s[threadIdx.x] = v;
    __syncthreads();
    #pragma unroll
    for (int st = 128; st > 0; st >>= 1) {
        if (threadIdx.x < st) s[threadIdx.x] += s[threadIdx.x + st];
        __syncthreads();
    }
    if (threadIdx.x == 0) out[0] = s[0] * 0.01f;
}

extern "C" void kernel_launch(void* const* d_in, const int* in_sizes, int n_in,
                              void* d_out, int out_size, void* d_ws, size_t ws_size,
                              hipStream_t stream)
{
    const float* lig_feat  = (const float*)d_in[0];
    const float* rec_feat  = (const float*)d_in[1];
    const float* lig_coord = (const float*)d_in[2];
    const float* rec_coord = (const float*)d_in[3];
    float* out = (float*)d_out;
    float* partial = (float*)d_ws;

    const dim3 grid(RN / BRT, LN / BLT, EN / EH);   // (32, 4, 4) = 512 blocks
    ff_mfma<<<grid, dim3(256), LDS_BYTES, stream>>>(
        lig_feat, rec_feat, lig_coord, rec_coord, partial);

    const int nPartial = (RN / BRT) * (LN / BLT) * (EN / EH);   // 512
    ff_reduce<<<1, 256, 0, stream>>>(partial, out, nPartial);
}